// Round 5
// baseline (714.778 us; speedup 1.0000x reference)
//
#include <hip/hip_runtime.h>
#include <hip/hip_bf16.h>

// Problem constants: B=2, S=2048, H=1024, G=256, E=8, M=2048, TOP_K=2
#define T_TOK 4096      // B*S
#define N_PAIR 8192     // T_TOK * 2
#define H_DIM 1024
#define M_DIM 2048
#define E_NUM 8

// prep-kernel block ranges (64k x 128n transpose tiles)
#define T_W1 2048       // (E*H/64)*(M/128) = 128*16
#define T_W2 4096       // (E*M/64)*(M/128) = 256*16
#define T_W3 2048       // (E*M/64)*(H/128) = 256*8
#define T_ROUT 1024     // 4096 tokens / 4 waves

using bf16x8 = __attribute__((ext_vector_type(8))) short;
using f32x4  = __attribute__((ext_vector_type(4))) float;

__device__ __forceinline__ unsigned short f2bf(float f) {
    unsigned int u = __builtin_bit_cast(unsigned int, f);
    u += 0x7fffu + ((u >> 16) & 1u);   // RNE
    return (unsigned short)(u >> 16);
}
__device__ __forceinline__ float bf2f(unsigned short u) {
    return __builtin_bit_cast(float, (unsigned int)u << 16);
}

// async global->LDS, 16B per lane; LDS dest is wave-uniform base + lane*16
__device__ __forceinline__ void async16(const unsigned short* g, unsigned short* l) {
    __builtin_amdgcn_global_load_lds(
        (const __attribute__((address_space(1))) void*)g,
        (__attribute__((address_space(3))) void*)l, 16, 0, 0);
}

// ---- K_prep: fused weight transposes (blocks [0, T_W1+T_W2+T_W3)) + routing ----
// v4 transpose: 64k x 128n tiles; thread pair writes full 128-byte output lines.
__global__ void k_prep(const float* __restrict__ W1, const float* __restrict__ W2,
                       const float* __restrict__ W3,
                       unsigned short* __restrict__ W1t, unsigned short* __restrict__ W2t,
                       unsigned short* __restrict__ W3t,
                       const float* __restrict__ x, const float* __restrict__ rms_w,
                       const float* __restrict__ wg_W, const float* __restrict__ genre,
                       const float* __restrict__ gg_W, const float* __restrict__ gg_b,
                       const float* __restrict__ wg_b,
                       int* __restrict__ tok_e, float* __restrict__ tok_w)
{
    __shared__ float ld[64][132];   // pad 132: phase-2 reads 2-way (free); 33 KB
    int bid = blockIdx.x;

    if (bid < T_W1 + T_W2 + T_W3) {
        // ---- transpose-convert one [64k x 128n] tile: W [E*K][N] fp32 -> Wt [E][N][K] bf16
        const float* W; unsigned short* Wt; int tile, kshift, ntshift, N, K;
        if (bid < T_W1)              { W = W1; Wt = W1t; tile = bid;                 K = H_DIM; N = M_DIM; kshift = 10; ntshift = 4; }
        else if (bid < T_W1 + T_W2)  { W = W2; Wt = W2t; tile = bid - T_W1;          K = M_DIM; N = M_DIM; kshift = 11; ntshift = 4; }
        else                         { W = W3; Wt = W3t; tile = bid - T_W1 - T_W2;   K = M_DIM; N = H_DIM; kshift = 11; ntshift = 3; }
        int r0 = (tile >> ntshift) * 64;                  // global row in [0, E*K)
        int n0 = (tile & ((1 << ntshift) - 1)) * 128;
        int t = threadIdx.x;
        // phase 1: 64 rows x 128 floats; 4 threads/row x 8 float4 each
        {
            int rr = t >> 2, c0 = t & 3;
            const float4* src = (const float4*)(W + (size_t)(r0 + rr) * N + n0);
#pragma unroll
            for (int cc = 0; cc < 8; cc++) {
                float4 v = src[c0 + cc * 4];
                float* d = &ld[rr][(c0 + cc * 4) * 4];
                d[0] = v.x; d[1] = v.y; d[2] = v.z; d[3] = v.w;
            }
        }
        __syncthreads();
        // phase 2: write [128n][64k] bf16; thread -> (n = t>>1, k-half = t&1 -> 32 k)
        {
            int n = t >> 1, khalf = t & 1;
            int kb = khalf * 32;
            int e = r0 >> kshift;
            int kloc = (r0 & (K - 1)) + kb;
            unsigned short* dst = Wt + ((size_t)e * N + (n0 + n)) * K + kloc;
#pragma unroll
            for (int blk = 0; blk < 4; blk++) {
                bf16x8 o;
#pragma unroll
                for (int q = 0; q < 8; q++) o[q] = (short)f2bf(ld[kb + blk * 8 + q][n]);
                *(bf16x8*)(dst + blk * 8) = o;
            }
        }
        return;
    }

    // ---- routing: RMSNorm + word gate + genre gate + softmax + top2 ----
    int wave = threadIdx.x >> 6, lane = threadIdx.x & 63;
    int tok = (bid - (T_W1 + T_W2 + T_W3)) * 4 + wave;
    int b = tok >> 11;
    const float* xr = x + (size_t)tok * H_DIM;
    float xv[16];
    float ss = 0.f;
#pragma unroll
    for (int j = 0; j < 16; j++) { xv[j] = xr[lane + 64 * j]; ss += xv[j] * xv[j]; }
#pragma unroll
    for (int off = 32; off > 0; off >>= 1) ss += __shfl_xor(ss, off);
    float rstd = rsqrtf(ss * (1.f / 1024.f) + 1e-6f);
    float g[8] = {0.f, 0.f, 0.f, 0.f, 0.f, 0.f, 0.f, 0.f};
#pragma unroll
    for (int gi0 = 0; gi0 < 4; gi0++) {
        int gi = lane + gi0 * 64;
        float gf = genre[b * 256 + gi];
        const float4* w4 = (const float4*)(gg_W + gi * 8);
        float4 wa = w4[0], wb = w4[1];
        g[0] += gf * wa.x; g[1] += gf * wa.y; g[2] += gf * wa.z; g[3] += gf * wa.w;
        g[4] += gf * wb.x; g[5] += gf * wb.y; g[6] += gf * wb.z; g[7] += gf * wb.w;
    }
#pragma unroll
    for (int j = 0; j < 16; j++) {
        int h = lane + 64 * j;
        float xn = xv[j] * rstd * rms_w[h];
        const float4* w4 = (const float4*)(wg_W + h * 8);
        float4 wa = w4[0], wb = w4[1];
        g[0] += xn * wa.x; g[1] += xn * wa.y; g[2] += xn * wa.z; g[3] += xn * wa.w;
        g[4] += xn * wb.x; g[5] += xn * wb.y; g[6] += xn * wb.z; g[7] += xn * wb.w;
    }
#pragma unroll
    for (int e = 0; e < 8; e++) {
#pragma unroll
        for (int off = 32; off > 0; off >>= 1) g[e] += __shfl_xor(g[e], off);
    }
    if (lane == 0) {
#pragma unroll
        for (int e = 0; e < 8; e++) g[e] += wg_b[e] + gg_b[e];
        float m = g[0];
        for (int e = 1; e < 8; e++) m = fmaxf(m, g[e]);
        float p[8], psum = 0.f;
        for (int e = 0; e < 8; e++) { p[e] = expf(g[e] - m); psum += p[e]; }
        int i0 = 0;
        for (int e = 1; e < 8; e++) if (p[e] > p[i0]) i0 = e;
        int i1 = (i0 == 0) ? 1 : 0;
        for (int e = 0; e < 8; e++) if (e != i0 && p[e] > p[i1]) i1 = e;
        float inv = 1.f / psum;
        tok_e[tok * 2] = i0;         tok_e[tok * 2 + 1] = i1;
        tok_w[tok * 2] = p[i0] * inv; tok_w[tok * 2 + 1] = p[i1] * inv;
    }
}

// ---- K_scan: histogram tok_e + exclusive scan (single block) ----
__global__ void k_scan(const int* __restrict__ tok_e, int* __restrict__ meta)
{
    __shared__ int cnt[8];
    int t = threadIdx.x;
    if (t < 8) cnt[t] = 0;
    __syncthreads();
    for (int p = t; p < N_PAIR; p += 256) atomicAdd(&cnt[tok_e[p]], 1);
    __syncthreads();
    if (t == 0) {
        int acc = 0;
        for (int e = 0; e < 8; e++) {
            meta[e] = cnt[e]; meta[8 + e] = acc; meta[16 + e] = acc; acc += cnt[e];
        }
    }
}

// ---- K_gather: gather token rows (fp32 -> bf16) into expert-sorted order ----
__global__ void k_gather(const float* __restrict__ x, const int* __restrict__ tok_e,
                         int* __restrict__ meta, int* __restrict__ pair_pos,
                         unsigned short* __restrict__ x_g)
{
    int wave = threadIdx.x >> 6, lane = threadIdx.x & 63;
    int p = blockIdx.x * 4 + wave;
    int t = p >> 1;
    int e = tok_e[p];
    int pos;
    if (lane == 0) {
        pos = atomicAdd(&meta[16 + e], 1);
        pair_pos[p] = pos;
    }
    pos = __shfl(pos, 0);
    const float4* src = (const float4*)(x + (size_t)t * H_DIM);
    ushort4* dst = (ushort4*)(x_g + (size_t)pos * H_DIM);
#pragma unroll
    for (int j = 0; j < 4; j++) {
        float4 v = src[lane + 64 * j];
        ushort4 o;
        o.x = f2bf(v.x); o.y = f2bf(v.y); o.z = f2bf(v.z); o.w = f2bf(v.w);
        dst[lane + 64 * j] = o;
    }
}

// ---- GEMM: C = A_seg @ Wt[e]^T (+bias, optional relu), bf16 out ----
// v6: BK=32, 3-buffer LDS (48 KB -> 3 blocks/CU static), 2-tile-deep prefetch
// with counted vmcnt. Why: 2-buffer depth-1 prefetch must drain the just-staged
// tile at each boundary (round-1: 305 us); depth-2 gives ~2 K-steps (~500 cy)
// of load coverage while KEEPING >= baseline co-residency. Schedule per iter t:
//   STAGE(tile t+2) ; s_waitcnt vmcnt(8)+s_barrier  (retires all but newest 8
//   loads = tiles t+1,t+2 -> tile t proven landed) ; COMPUTE(t%3) ; s_barrier.
// XOR swizzle (4 chunks/row): LDS slot s of row r holds global chunk s^(r&3);
// read XORs identically -> same involution both sides (guide rule #21).
// XCD swizzle REVERTED: expert-per-XCD pinning created data-dependent XCD
// imbalance (round-4: FETCH 250->79 MB but dur 122->135 us). Default dispatch
// already gives B-panels perfect XCD affinity (same bx => same id%8).
template<bool RELU>
__global__ void k_gemm(const unsigned short* __restrict__ A,
                       const unsigned short* __restrict__ Wt,
                       const float* __restrict__ bias,
                       unsigned short* __restrict__ C,
                       const int* __restrict__ meta,
                       int K, int N)
{
    int e = blockIdx.z;
    int cnt = meta[e];
    int by = blockIdx.y;
    if (by * 128 >= cnt) return;
    int base = meta[8 + e];
    int bx = blockIdx.x;

    __shared__ __align__(16) unsigned short AsF[3 * 128 * 32];   // 24 KB
    __shared__ __align__(16) unsigned short BsF[3 * 128 * 32];   // 24 KB

    int tid = threadIdx.x;
    int wave = tid >> 6, lane = tid & 63;
    int lrow = lane >> 2;                       // 0..15: row within 16-row staging round
    int chunk_g = ((lane & 3) ^ (lrow & 3)) * 8; // global chunk offset (shorts), row&3 == lrow&3

    const unsigned short* Bw = Wt + (size_t)e * N * K + (size_t)(bx * 128) * K;
    const unsigned short* gA[2]; const unsigned short* gB[2];
    int sAB[2];
#pragma unroll
    for (int c = 0; c < 2; c++) {
        int rloc = wave * 32 + c * 16 + lrow;
        int ra = base + by * 128 + rloc;
        ra = min(ra, N_PAIR - 1);               // clamp: garbage rows discarded in epilogue
        gA[c] = A + (size_t)ra * K + chunk_g;
        gB[c] = Bw + (size_t)rloc * K + chunk_g;
        sAB[c] = (wave * 32 + c * 16) * 32;     // LDS group offset within a buffer (shorts)
    }

    int wr = (wave >> 1) * 64, wc = (wave & 1) * 64;
    int lm = lane & 15, lq = lane >> 4;

    // fixed LDS read offsets (shorts) within a buffer, frag i
    int aoff[4], boff[4];
#pragma unroll
    for (int i = 0; i < 4; i++) {
        int R = wr + i * 16 + lm;
        aoff[i] = R * 32 + ((lq ^ (R & 3)) * 8);
        int Nn = wc + i * 16 + lm;
        boff[i] = Nn * 32 + ((lq ^ (Nn & 3)) * 8);
    }

    f32x4 acc[4][4] = {};

#define STAGE(sb, T)                                                          \
    {                                                                         \
        _Pragma("unroll")                                                     \
        for (int c = 0; c < 2; c++) {                                         \
            async16(gA[c] + (T) * 32, &AsF[(sb) * 4096 + sAB[c]]);            \
            async16(gB[c] + (T) * 32, &BsF[(sb) * 4096 + sAB[c]]);            \
        }                                                                     \
    }

#define COMPUTE(cb)                                                           \
    {                                                                         \
        const unsigned short* Ab = &AsF[(cb) * 4096];                         \
        const unsigned short* Bb = &BsF[(cb) * 4096];                         \
        bf16x8 af[4], bfr[4];                                                 \
        _Pragma("unroll")                                                     \
        for (int i = 0; i < 4; i++) af[i] = *(const bf16x8*)&Ab[aoff[i]];     \
        _Pragma("unroll")                                                     \
        for (int j = 0; j < 4; j++) bfr[j] = *(const bf16x8*)&Bb[boff[j]];    \
        _Pragma("unroll")                                                     \
        for (int i = 0; i < 4; i++)                                           \
            _Pragma("unroll")                                                 \
            for (int j = 0; j < 4; j++)                                       \
                acc[i][j] = __builtin_amdgcn_mfma_f32_16x16x32_bf16(af[i], bfr[j], acc[i][j], 0, 0, 0); \
    }

    int nt = K >> 5;                            // 32 (K=1024) or 64 (K=2048)

    // prologue: stage tiles 0 and 1 (no wait yet; first wait inside loop)
    STAGE(0, 0);
    STAGE(1, 1);

    int sb = 2, cb = 0;
#pragma unroll 1
    for (int t = 0; t <= nt - 3; ++t) {
        STAGE(sb, t + 2);
        sb = (sb == 2) ? 0 : sb + 1;
        // retire all but newest 8 loads (tiles t+1,t+2) -> tile t landed; sync waves
        asm volatile("s_waitcnt vmcnt(8)\n\ts_barrier" ::: "memory");
        COMPUTE(cb);
        cb = (cb == 2) ? 0 : cb + 1;
        asm volatile("s_barrier" ::: "memory"); // all reads of tile t done before overwrite
    }
    // epilogue: tiles nt-2, nt-1 (no further staging)
    asm volatile("s_waitcnt vmcnt(4)\n\ts_barrier" ::: "memory");
    COMPUTE(cb);
    cb = (cb == 2) ? 0 : cb + 1;
    asm volatile("s_waitcnt vmcnt(0)\n\ts_barrier" ::: "memory");
    COMPUTE(cb);

#undef STAGE
#undef COMPUTE

#pragma unroll
    for (int j = 0; j < 4; j++) {
        int n = bx * 128 + wc + j * 16 + lm;
        float bv = bias[(size_t)e * N + n];
#pragma unroll
        for (int i = 0; i < 4; i++) {
#pragma unroll
            for (int r = 0; r < 4; r++) {
                int grow = by * 128 + wr + i * 16 + lq * 4 + r;
                if (grow < cnt) {
                    float v = acc[i][j][r] + bv;
                    if (RELU) v = fmaxf(v, 0.f);
                    C[(size_t)(base + grow) * N + n] = f2bf(v);
                }
            }
        }
    }
}

// ---- K_combine: out[t] = w0*o3[pos(t,0)] + w1*o3[pos(t,1)] (o3 bf16) ----
__global__ void k_combine(const unsigned short* __restrict__ o3,
                          const int* __restrict__ pair_pos,
                          const float* __restrict__ tok_w, float* __restrict__ out)
{
    int t = blockIdx.x;
    int c = threadIdx.x;                 // 256 threads x 4 elems = 1024
    int p0 = pair_pos[t * 2], p1 = pair_pos[t * 2 + 1];
    float w0 = tok_w[t * 2], w1 = tok_w[t * 2 + 1];
    ushort4 a = ((const ushort4*)(o3 + (size_t)p0 * H_DIM))[c];
    ushort4 bq = ((const ushort4*)(o3 + (size_t)p1 * H_DIM))[c];
    float4 o;
    o.x = w0 * bf2f(a.x) + w1 * bf2f(bq.x);
    o.y = w0 * bf2f(a.y) + w1 * bf2f(bq.y);
    o.z = w0 * bf2f(a.z) + w1 * bf2f(bq.z);
    o.w = w0 * bf2f(a.w) + w1 * bf2f(bq.w);
    ((float4*)(out + (size_t)t * H_DIM))[c] = o;
}

extern "C" void kernel_launch(void* const* d_in, const int* in_sizes, int n_in,
                              void* d_out, int out_size, void* d_ws, size_t ws_size,
                              hipStream_t stream) {
    const float* x      = (const float*)d_in[0];
    const float* genre  = (const float*)d_in[1];
    const float* rms_w  = (const float*)d_in[2];
    const float* wg_W   = (const float*)d_in[3];
    const float* wg_b   = (const float*)d_in[4];
    const float* gg_W   = (const float*)d_in[5];
    const float* gg_b   = (const float*)d_in[6];
    const float* W1     = (const float*)d_in[7];
    const float* b1     = (const float*)d_in[8];
    const float* W2     = (const float*)d_in[9];
    const float* b2     = (const float*)d_in[10];
    const float* W3     = (const float*)d_in[11];
    const float* b3     = (const float*)d_in[12];
    float* out = (float*)d_out;

    char* p = (char*)d_ws;
    auto alloc = [&](size_t bytes) { char* r = p; p += (bytes + 255) & ~(size_t)255; return r; };
    unsigned short* W1t = (unsigned short*)alloc((size_t)E_NUM * H_DIM * M_DIM * 2);
    unsigned short* W2t = (unsigned short*)alloc((size_t)E_NUM * M_DIM * M_DIM * 2);
    unsigned short* W3t = (unsigned short*)alloc((size_t)E_NUM * M_DIM * H_DIM * 2);
    unsigned short* x_g = (unsigned short*)alloc((size_t)N_PAIR * H_DIM * 2);
    unsigned short* h1  = (unsigned short*)alloc((size_t)N_PAIR * M_DIM * 2);
    unsigned short* h2  = (unsigned short*)alloc((size_t)N_PAIR * M_DIM * 2);
    unsigned short* o3  = (unsigned short*)alloc((size_t)N_PAIR * H_DIM * 2);
    int*   meta         = (int*)alloc(24 * 4);      // counts[8], bases[8], fills[8]
    int*   tok_e        = (int*)alloc((size_t)N_PAIR * 4);
    float* tok_w        = (float*)alloc((size_t)N_PAIR * 4);
    int*   pair_pos     = (int*)alloc((size_t)N_PAIR * 4);

    dim3 blk(256);

    k_prep<<<T_W1 + T_W2 + T_W3 + T_ROUT, blk, 0, stream>>>(
        W1, W2, W3, W1t, W2t, W3t, x, rms_w, wg_W, genre, gg_W, gg_b, wg_b,
        tok_e, tok_w);
    k_scan<<<1, blk, 0, stream>>>(tok_e, meta);
    k_gather<<<N_PAIR / 4, blk, 0, stream>>>(x, tok_e, meta, pair_pos, x_g);

    // expert GEMMs: worst-case 32 row tiles per expert, early-exit on count
    k_gemm<true ><<<dim3(M_DIM / 128, 32, E_NUM), blk, 0, stream>>>(
        x_g, W1t, b1, h1, meta, H_DIM, M_DIM);
    k_gemm<true ><<<dim3(M_DIM / 128, 32, E_NUM), blk, 0, stream>>>(
        h1, W2t, b2, h2, meta, M_DIM, M_DIM);
    k_gemm<false><<<dim3(H_DIM / 128, 32, E_NUM), blk, 0, stream>>>(
        h2, W3t, b3, o3, meta, M_DIM, H_DIM);

    k_combine<<<T_TOK, blk, 0, stream>>>(o3, pair_pos, tok_w, out);

    (void)in_sizes; (void)n_in; (void)ws_size;
}

// Round 6
// 676.819 us; speedup vs baseline: 1.0561x; 1.0561x over previous
//
#include <hip/hip_runtime.h>
#include <hip/hip_bf16.h>

// Problem constants: B=2, S=2048, H=1024, G=256, E=8, M=2048, TOP_K=2
#define T_TOK 4096      // B*S
#define N_PAIR 8192     // T_TOK * 2
#define H_DIM 1024
#define M_DIM 2048
#define E_NUM 8

// prep-kernel block ranges (64k x 128n transpose tiles)
#define T_W1 2048       // (E*H/64)*(M/128) = 128*16
#define T_W2 4096       // (E*M/64)*(M/128) = 256*16
#define T_W3 2048       // (E*M/64)*(H/128) = 256*8
#define T_ROUT 1024     // 4096 tokens / 4 waves

using bf16x8 = __attribute__((ext_vector_type(8))) short;
using f32x4  = __attribute__((ext_vector_type(4))) float;

__device__ __forceinline__ unsigned short f2bf(float f) {
    unsigned int u = __builtin_bit_cast(unsigned int, f);
    u += 0x7fffu + ((u >> 16) & 1u);   // RNE
    return (unsigned short)(u >> 16);
}
__device__ __forceinline__ float bf2f(unsigned short u) {
    return __builtin_bit_cast(float, (unsigned int)u << 16);
}

// async global->LDS, 16B per lane; LDS dest is wave-uniform base + lane*16
__device__ __forceinline__ void async16(const unsigned short* g, unsigned short* l) {
    __builtin_amdgcn_global_load_lds(
        (const __attribute__((address_space(1))) void*)g,
        (__attribute__((address_space(3))) void*)l, 16, 0, 0);
}

// ---- K_prep: fused weight transposes (blocks [0, T_W1+T_W2+T_W3)) + routing ----
// v4 transpose: 64k x 128n tiles; thread pair writes full 128-byte output lines.
__global__ void k_prep(const float* __restrict__ W1, const float* __restrict__ W2,
                       const float* __restrict__ W3,
                       unsigned short* __restrict__ W1t, unsigned short* __restrict__ W2t,
                       unsigned short* __restrict__ W3t,
                       const float* __restrict__ x, const float* __restrict__ rms_w,
                       const float* __restrict__ wg_W, const float* __restrict__ genre,
                       const float* __restrict__ gg_W, const float* __restrict__ gg_b,
                       const float* __restrict__ wg_b,
                       int* __restrict__ tok_e, float* __restrict__ tok_w)
{
    __shared__ float ld[64][132];   // pad 132: phase-2 reads 2-way (free); 33 KB
    int bid = blockIdx.x;

    if (bid < T_W1 + T_W2 + T_W3) {
        // ---- transpose-convert one [64k x 128n] tile: W [E*K][N] fp32 -> Wt [E][N][K] bf16
        const float* W; unsigned short* Wt; int tile, kshift, ntshift, N, K;
        if (bid < T_W1)              { W = W1; Wt = W1t; tile = bid;                 K = H_DIM; N = M_DIM; kshift = 10; ntshift = 4; }
        else if (bid < T_W1 + T_W2)  { W = W2; Wt = W2t; tile = bid - T_W1;          K = M_DIM; N = M_DIM; kshift = 11; ntshift = 4; }
        else                         { W = W3; Wt = W3t; tile = bid - T_W1 - T_W2;   K = M_DIM; N = H_DIM; kshift = 11; ntshift = 3; }
        int r0 = (tile >> ntshift) * 64;                  // global row in [0, E*K)
        int n0 = (tile & ((1 << ntshift) - 1)) * 128;
        int t = threadIdx.x;
        // phase 1: 64 rows x 128 floats; 4 threads/row x 8 float4 each
        {
            int rr = t >> 2, c0 = t & 3;
            const float4* src = (const float4*)(W + (size_t)(r0 + rr) * N + n0);
#pragma unroll
            for (int cc = 0; cc < 8; cc++) {
                float4 v = src[c0 + cc * 4];
                float* d = &ld[rr][(c0 + cc * 4) * 4];
                d[0] = v.x; d[1] = v.y; d[2] = v.z; d[3] = v.w;
            }
        }
        __syncthreads();
        // phase 2: write [128n][64k] bf16; thread -> (n = t>>1, k-half = t&1 -> 32 k)
        {
            int n = t >> 1, khalf = t & 1;
            int kb = khalf * 32;
            int e = r0 >> kshift;
            int kloc = (r0 & (K - 1)) + kb;
            unsigned short* dst = Wt + ((size_t)e * N + (n0 + n)) * K + kloc;
#pragma unroll
            for (int blk = 0; blk < 4; blk++) {
                bf16x8 o;
#pragma unroll
                for (int q = 0; q < 8; q++) o[q] = (short)f2bf(ld[kb + blk * 8 + q][n]);
                *(bf16x8*)(dst + blk * 8) = o;
            }
        }
        return;
    }

    // ---- routing: RMSNorm + word gate + genre gate + softmax + top2 ----
    int wave = threadIdx.x >> 6, lane = threadIdx.x & 63;
    int tok = (bid - (T_W1 + T_W2 + T_W3)) * 4 + wave;
    int b = tok >> 11;
    const float* xr = x + (size_t)tok * H_DIM;
    float xv[16];
    float ss = 0.f;
#pragma unroll
    for (int j = 0; j < 16; j++) { xv[j] = xr[lane + 64 * j]; ss += xv[j] * xv[j]; }
#pragma unroll
    for (int off = 32; off > 0; off >>= 1) ss += __shfl_xor(ss, off);
    float rstd = rsqrtf(ss * (1.f / 1024.f) + 1e-6f);
    float g[8] = {0.f, 0.f, 0.f, 0.f, 0.f, 0.f, 0.f, 0.f};
#pragma unroll
    for (int gi0 = 0; gi0 < 4; gi0++) {
        int gi = lane + gi0 * 64;
        float gf = genre[b * 256 + gi];
        const float4* w4 = (const float4*)(gg_W + gi * 8);
        float4 wa = w4[0], wb = w4[1];
        g[0] += gf * wa.x; g[1] += gf * wa.y; g[2] += gf * wa.z; g[3] += gf * wa.w;
        g[4] += gf * wb.x; g[5] += gf * wb.y; g[6] += gf * wb.z; g[7] += gf * wb.w;
    }
#pragma unroll
    for (int j = 0; j < 16; j++) {
        int h = lane + 64 * j;
        float xn = xv[j] * rstd * rms_w[h];
        const float4* w4 = (const float4*)(wg_W + h * 8);
        float4 wa = w4[0], wb = w4[1];
        g[0] += xn * wa.x; g[1] += xn * wa.y; g[2] += xn * wa.z; g[3] += xn * wa.w;
        g[4] += xn * wb.x; g[5] += xn * wb.y; g[6] += xn * wb.z; g[7] += xn * wb.w;
    }
#pragma unroll
    for (int e = 0; e < 8; e++) {
#pragma unroll
        for (int off = 32; off > 0; off >>= 1) g[e] += __shfl_xor(g[e], off);
    }
    if (lane == 0) {
#pragma unroll
        for (int e = 0; e < 8; e++) g[e] += wg_b[e] + gg_b[e];
        float m = g[0];
        for (int e = 1; e < 8; e++) m = fmaxf(m, g[e]);
        float p[8], psum = 0.f;
        for (int e = 0; e < 8; e++) { p[e] = expf(g[e] - m); psum += p[e]; }
        int i0 = 0;
        for (int e = 1; e < 8; e++) if (p[e] > p[i0]) i0 = e;
        int i1 = (i0 == 0) ? 1 : 0;
        for (int e = 0; e < 8; e++) if (e != i0 && p[e] > p[i1]) i1 = e;
        float inv = 1.f / psum;
        tok_e[tok * 2] = i0;         tok_e[tok * 2 + 1] = i1;
        tok_w[tok * 2] = p[i0] * inv; tok_w[tok * 2 + 1] = p[i1] * inv;
    }
}

// ---- K_scan: histogram tok_e + exclusive scan (single block) ----
__global__ void k_scan(const int* __restrict__ tok_e, int* __restrict__ meta)
{
    __shared__ int cnt[8];
    int t = threadIdx.x;
    if (t < 8) cnt[t] = 0;
    __syncthreads();
    for (int p = t; p < N_PAIR; p += 256) atomicAdd(&cnt[tok_e[p]], 1);
    __syncthreads();
    if (t == 0) {
        int acc = 0;
        for (int e = 0; e < 8; e++) {
            meta[e] = cnt[e]; meta[8 + e] = acc; meta[16 + e] = acc; acc += cnt[e];
        }
    }
}

// ---- K_gather: gather token rows (fp32 -> bf16) into expert-sorted order ----
__global__ void k_gather(const float* __restrict__ x, const int* __restrict__ tok_e,
                         int* __restrict__ meta, int* __restrict__ pair_pos,
                         unsigned short* __restrict__ x_g)
{
    int wave = threadIdx.x >> 6, lane = threadIdx.x & 63;
    int p = blockIdx.x * 4 + wave;
    int t = p >> 1;
    int e = tok_e[p];
    int pos;
    if (lane == 0) {
        pos = atomicAdd(&meta[16 + e], 1);
        pair_pos[p] = pos;
    }
    pos = __shfl(pos, 0);
    const float4* src = (const float4*)(x + (size_t)t * H_DIM);
    ushort4* dst = (ushort4*)(x_g + (size_t)pos * H_DIM);
#pragma unroll
    for (int j = 0; j < 4; j++) {
        float4 v = src[lane + 64 * j];
        ushort4 o;
        o.x = f2bf(v.x); o.y = f2bf(v.y); o.z = f2bf(v.z); o.w = f2bf(v.w);
        dst[lane + 64 * j] = o;
    }
}

// ---- GEMM: C = A_seg @ Wt[e]^T (+bias, optional relu), bf16 out ----
// v7: round-0 proven shell (BK=64, 32 KB single buffer, conflict-free XOR
// swizzle, ~3 blocks/CU) + MFMA-covered staging:
//   per K-step: ds_read ALL 16 frags -> lgkmcnt(0)+s_barrier (tile now in
//   regs, LDS free) -> STAGE(next) into the SAME buffer -> sched_barrier(0)
//   (pin issue order) -> setprio(1)+32 MFMA+setprio(0) (covers in-flight
//   loads) -> vmcnt(0)+s_barrier (next tile landed).
// vs round-0: the vmcnt drain sits after the MFMA cluster, not right after
// load issue. vs rounds 1/5: LDS/occupancy unchanged, swizzle unchanged.
// __launch_bounds__(256,2): raise VGPR cap (frags 64 + acc 64 + addr);
// round-1's 2.5x regression was SPILL (WRITE_SIZE 257 MB) from the default
// 64-VGPR cap. Failed variants (do not re-add): 64KB syncthreads-dbuf
// (305us, spill+occupancy), BK=32 3-buf (135us, 4-way LDS conflict — only
// 4 chunk slots per 64B row can't tile 32 banks), expert-per-XCD swizzle
// (135us, data-dependent XCD imbalance).
template<bool RELU>
__global__ __launch_bounds__(256, 2)
void k_gemm(const unsigned short* __restrict__ A,
            const unsigned short* __restrict__ Wt,
            const float* __restrict__ bias,
            unsigned short* __restrict__ C,
            const int* __restrict__ meta,
            int K, int N)
{
    int e = blockIdx.z;
    int cnt = meta[e];
    int by = blockIdx.y;
    if (by * 128 >= cnt) return;
    int base = meta[8 + e];
    int bx = blockIdx.x;

    __shared__ __align__(16) unsigned short As[128 * 64];
    __shared__ __align__(16) unsigned short Bs[128 * 64];

    int tid = threadIdx.x;
    int wave = tid >> 6, lane = tid & 63;
    int lrow8 = lane >> 3;                      // 0..7: row within 8-row staging group
    int lslot = lane & 7;                       // LDS chunk slot
    int chunk_g = (lslot ^ lrow8) * 8;          // global chunk offset (shorts)

    const unsigned short* Bw = Wt + (size_t)e * N * K + (size_t)(bx * 128) * K;
    const unsigned short* gA[4]; const unsigned short* gB[4];
    unsigned short* lA[4]; unsigned short* lB[4];
#pragma unroll
    for (int c = 0; c < 4; c++) {
        int rloc = wave * 32 + c * 8 + lrow8;
        int ra = base + by * 128 + rloc;
        ra = min(ra, N_PAIR - 1);               // clamp: garbage rows discarded in epilogue
        gA[c] = A + (size_t)ra * K + chunk_g;
        gB[c] = Bw + (size_t)rloc * K + chunk_g;
        lA[c] = &As[(wave * 32 + c * 8) * 64];
        lB[c] = &Bs[(wave * 32 + c * 8) * 64];
    }

    int wr = (wave >> 1) * 64, wc = (wave & 1) * 64;
    int lm = lane & 15, lq = lane >> 4;

    // fixed LDS read offsets (shorts): frag (i, k-half h)
    int aoff[4][2], boff[4][2];
#pragma unroll
    for (int i = 0; i < 4; i++)
#pragma unroll
        for (int h = 0; h < 2; h++) {
            int R = wr + i * 16 + lm;
            aoff[i][h] = R * 64 + (((h * 4 + lq) ^ (R & 7)) * 8);
            int Nn = wc + i * 16 + lm;
            boff[i][h] = Nn * 64 + (((h * 4 + lq) ^ (Nn & 7)) * 8);
        }

    f32x4 acc[4][4] = {};

    // prologue: stage tile 0, wait, sync
    {
#pragma unroll
        for (int c = 0; c < 4; c++) { async16(gA[c], lA[c]); async16(gB[c], lB[c]); }
        asm volatile("s_waitcnt vmcnt(0)" ::: "memory");
        __builtin_amdgcn_s_barrier();
    }

#pragma unroll 1
    for (int kt = 0; kt < K; kt += 64) {
        // 1) tile kt -> registers (16 x ds_read_b128)
        bf16x8 af[4][2], bfr[4][2];
#pragma unroll
        for (int h = 0; h < 2; h++) {
#pragma unroll
            for (int i = 0; i < 4; i++) af[i][h]  = *(const bf16x8*)&As[aoff[i][h]];
#pragma unroll
            for (int j = 0; j < 4; j++) bfr[j][h] = *(const bf16x8*)&Bs[boff[j][h]];
        }
        asm volatile("s_waitcnt lgkmcnt(0)" ::: "memory");
        __builtin_amdgcn_s_barrier();           // all waves hold tile kt in regs
        // 2) stage tile kt+64 into the same buffer (legal: LDS reads done)
        if (kt + 64 < K) {
#pragma unroll
            for (int c = 0; c < 4; c++) { async16(gA[c] + kt + 64, lA[c]); async16(gB[c] + kt + 64, lB[c]); }
        }
        __builtin_amdgcn_sched_barrier(0);      // loads issued before MFMA cluster
        // 3) MFMA cluster covers the in-flight loads
        __builtin_amdgcn_s_setprio(1);
#pragma unroll
        for (int h = 0; h < 2; h++)
#pragma unroll
            for (int i = 0; i < 4; i++)
#pragma unroll
                for (int j = 0; j < 4; j++)
                    acc[i][j] = __builtin_amdgcn_mfma_f32_16x16x32_bf16(af[i][h], bfr[j][h], acc[i][j], 0, 0, 0);
        __builtin_amdgcn_s_setprio(0);
        // 4) next tile landed + synced
        if (kt + 64 < K) {
            asm volatile("s_waitcnt vmcnt(0)" ::: "memory");
            __builtin_amdgcn_s_barrier();
        }
    }

#pragma unroll
    for (int j = 0; j < 4; j++) {
        int n = bx * 128 + wc + j * 16 + lm;
        float bv = bias[(size_t)e * N + n];
#pragma unroll
        for (int i = 0; i < 4; i++) {
#pragma unroll
            for (int r = 0; r < 4; r++) {
                int grow = by * 128 + wr + i * 16 + lq * 4 + r;
                if (grow < cnt) {
                    float v = acc[i][j][r] + bv;
                    if (RELU) v = fmaxf(v, 0.f);
                    C[(size_t)(base + grow) * N + n] = f2bf(v);
                }
            }
        }
    }
}

// ---- K_combine: out[t] = w0*o3[pos(t,0)] + w1*o3[pos(t,1)] (o3 bf16) ----
__global__ void k_combine(const unsigned short* __restrict__ o3,
                          const int* __restrict__ pair_pos,
                          const float* __restrict__ tok_w, float* __restrict__ out)
{
    int t = blockIdx.x;
    int c = threadIdx.x;                 // 256 threads x 4 elems = 1024
    int p0 = pair_pos[t * 2], p1 = pair_pos[t * 2 + 1];
    float w0 = tok_w[t * 2], w1 = tok_w[t * 2 + 1];
    ushort4 a = ((const ushort4*)(o3 + (size_t)p0 * H_DIM))[c];
    ushort4 bq = ((const ushort4*)(o3 + (size_t)p1 * H_DIM))[c];
    float4 o;
    o.x = w0 * bf2f(a.x) + w1 * bf2f(bq.x);
    o.y = w0 * bf2f(a.y) + w1 * bf2f(bq.y);
    o.z = w0 * bf2f(a.z) + w1 * bf2f(bq.z);
    o.w = w0 * bf2f(a.w) + w1 * bf2f(bq.w);
    ((float4*)(out + (size_t)t * H_DIM))[c] = o;
}

extern "C" void kernel_launch(void* const* d_in, const int* in_sizes, int n_in,
                              void* d_out, int out_size, void* d_ws, size_t ws_size,
                              hipStream_t stream) {
    const float* x      = (const float*)d_in[0];
    const float* genre  = (const float*)d_in[1];
    const float* rms_w  = (const float*)d_in[2];
    const float* wg_W   = (const float*)d_in[3];
    const float* wg_b   = (const float*)d_in[4];
    const float* gg_W   = (const float*)d_in[5];
    const float* gg_b   = (const float*)d_in[6];
    const float* W1     = (const float*)d_in[7];
    const float* b1     = (const float*)d_in[8];
    const float* W2     = (const float*)d_in[9];
    const float* b2     = (const float*)d_in[10];
    const float* W3     = (const float*)d_in[11];
    const float* b3     = (const float*)d_in[12];
    float* out = (float*)d_out;

    char* p = (char*)d_ws;
    auto alloc = [&](size_t bytes) { char* r = p; p += (bytes + 255) & ~(size_t)255; return r; };
    unsigned short* W1t = (unsigned short*)alloc((size_t)E_NUM * H_DIM * M_DIM * 2);
    unsigned short* W2t = (unsigned short*)alloc((size_t)E_NUM * M_DIM * M_DIM * 2);
    unsigned short* W3t = (unsigned short*)alloc((size_t)E_NUM * M_DIM * H_DIM * 2);
    unsigned short* x_g = (unsigned short*)alloc((size_t)N_PAIR * H_DIM * 2);
    unsigned short* h1  = (unsigned short*)alloc((size_t)N_PAIR * M_DIM * 2);
    unsigned short* h2  = (unsigned short*)alloc((size_t)N_PAIR * M_DIM * 2);
    unsigned short* o3  = (unsigned short*)alloc((size_t)N_PAIR * H_DIM * 2);
    int*   meta         = (int*)alloc(24 * 4);      // counts[8], bases[8], fills[8]
    int*   tok_e        = (int*)alloc((size_t)N_PAIR * 4);
    float* tok_w        = (float*)alloc((size_t)N_PAIR * 4);
    int*   pair_pos     = (int*)alloc((size_t)N_PAIR * 4);

    dim3 blk(256);

    k_prep<<<T_W1 + T_W2 + T_W3 + T_ROUT, blk, 0, stream>>>(
        W1, W2, W3, W1t, W2t, W3t, x, rms_w, wg_W, genre, gg_W, gg_b, wg_b,
        tok_e, tok_w);
    k_scan<<<1, blk, 0, stream>>>(tok_e, meta);
    k_gather<<<N_PAIR / 4, blk, 0, stream>>>(x, tok_e, meta, pair_pos, x_g);

    // expert GEMMs: worst-case 32 row tiles per expert, early-exit on count
    k_gemm<true ><<<dim3(M_DIM / 128, 32, E_NUM), blk, 0, stream>>>(
        x_g, W1t, b1, h1, meta, H_DIM, M_DIM);
    k_gemm<true ><<<dim3(M_DIM / 128, 32, E_NUM), blk, 0, stream>>>(
        h1, W2t, b2, h2, meta, M_DIM, M_DIM);
    k_gemm<false><<<dim3(H_DIM / 128, 32, E_NUM), blk, 0, stream>>>(
        h2, W3t, b3, o3, meta, M_DIM, H_DIM);

    k_combine<<<T_TOK, blk, 0, stream>>>(o3, pair_pos, tok_w, out);

    (void)in_sizes; (void)n_in; (void)ws_size;
}